// Round 1
// baseline (382.565 us; speedup 1.0000x reference)
//
#include <hip/hip_runtime.h>

// Problem constants
// x_restored: (8192, 3, 20, 20) f32
// x_distorted: (8192, 5) f32
// w1: (128, 5), w2: (1200, 128), b2: (1200,)
// conv_w: (15, 6, 3, 3), conv_b: (15,)
// out: (8192, 5, 3, 20, 20) f32

#define NB 8192

// ---------------- Kernel A: h = relu(x_distorted @ w1.T), h: (B,128) ----------------
__global__ __launch_bounds__(256) void mlp1_kernel(const float* __restrict__ xdist,
                                                   const float* __restrict__ w1,
                                                   float* __restrict__ h) {
    int gid = blockIdx.x * 256 + threadIdx.x;
    int b = gid >> 7, j = gid & 127;
    const float* xr = xdist + b * 5;
    const float* wr = w1 + j * 5;
    float s = xr[0] * wr[0];
    s = fmaf(xr[1], wr[1], s);
    s = fmaf(xr[2], wr[2], s);
    s = fmaf(xr[3], wr[3], s);
    s = fmaf(xr[4], wr[4], s);
    h[gid] = fmaxf(s, 0.0f);
}

// ---------------- Kernel B: xd = h @ w2.T + b2, xd: (B,1200) ----------------
// Block handles 32 rows x 1200 cols. Each thread owns cols n = tid (mod 256).
// w2 row per-lane from global (L2 resident); h via wave-uniform scalar loads.
__global__ __launch_bounds__(256) void mlp2_kernel(const float* __restrict__ h,
                                                   const float* __restrict__ w2,
                                                   const float* __restrict__ b2,
                                                   float* __restrict__ xd) {
    const int rbase = blockIdx.x * 32;
    const int tid = threadIdx.x;
    for (int n = tid; n < 1200; n += 256) {
        float acc[32];
        float bias = b2[n];
        #pragma unroll
        for (int r = 0; r < 32; ++r) acc[r] = bias;
        const float4* w2row = reinterpret_cast<const float4*>(w2 + n * 128);
        #pragma unroll
        for (int kc = 0; kc < 8; ++kc) {
            float4 a0 = w2row[kc * 4 + 0];
            float4 a1 = w2row[kc * 4 + 1];
            float4 a2 = w2row[kc * 4 + 2];
            float4 a3 = w2row[kc * 4 + 3];
            #pragma unroll
            for (int r = 0; r < 32; ++r) {
                const float* hr = h + (rbase + r) * 128 + kc * 16;  // uniform -> s_load
                float t = acc[r];
                t = fmaf(a0.x, hr[0], t);
                t = fmaf(a0.y, hr[1], t);
                t = fmaf(a0.z, hr[2], t);
                t = fmaf(a0.w, hr[3], t);
                t = fmaf(a1.x, hr[4], t);
                t = fmaf(a1.y, hr[5], t);
                t = fmaf(a1.z, hr[6], t);
                t = fmaf(a1.w, hr[7], t);
                t = fmaf(a2.x, hr[8], t);
                t = fmaf(a2.y, hr[9], t);
                t = fmaf(a2.z, hr[10], t);
                t = fmaf(a2.w, hr[11], t);
                t = fmaf(a3.x, hr[12], t);
                t = fmaf(a3.y, hr[13], t);
                t = fmaf(a3.z, hr[14], t);
                t = fmaf(a3.w, hr[15], t);
                acc[r] = t;
            }
        }
        #pragma unroll
        for (int r = 0; r < 32; ++r) xd[(size_t)(rbase + r) * 1200 + n] = acc[r];
    }
}

// ---------------- Kernel C: conv(6->15, 3x3 SAME) + Gram-Schmidt, one block per sample ----
// 256 threads. Thread owns positions p = tid and p = tid + 256 (if < 400), all 15 out chans
// in registers. GS dots via shfl + tiny LDS reduce; AXPY is register-only.
__global__ __launch_bounds__(256) void conv_gs_kernel(const float* __restrict__ xd,
                                                      const float* __restrict__ xres,
                                                      const float* __restrict__ cw,
                                                      const float* __restrict__ cb,
                                                      float* __restrict__ out) {
    const int b = blockIdx.x;
    const int tid = threadIdx.x;
    __shared__ float xpad[6][22][22];  // zero-padded input, 11.6 KB
    __shared__ float red[4];

    // zero padding region
    float* xf = &xpad[0][0][0];
    for (int i = tid; i < 6 * 22 * 22; i += 256) xf[i] = 0.0f;
    __syncthreads();

    // fill interior: channels 0..2 = xd, 3..5 = x_restored
    const float* src0 = xd + (size_t)b * 1200;
    const float* src1 = xres + (size_t)b * 1200;
    for (int i = tid; i < 2400; i += 256) {
        int c = i / 400;
        int r = i % 400;
        int y = r / 20, x = r % 20;
        float v = (c < 3) ? src0[i] : src1[i - 1200];
        xpad[c][y + 1][x + 1] = v;
    }
    __syncthreads();

    // conv into registers
    float acc[2][15];
    const bool has1 = (tid < 144);   // tid + 256 < 400
    int p0 = tid;
    int p1 = has1 ? (tid + 256) : 0;
    #pragma unroll
    for (int o = 0; o < 15; ++o) {
        float bo = cb[o];            // uniform -> s_load
        acc[0][o] = bo;
        acc[1][o] = bo;
    }
    const int y0 = p0 / 20, x0 = p0 % 20;
    const int y1 = p1 / 20, x1 = p1 % 20;

    #pragma unroll
    for (int ci = 0; ci < 6; ++ci) {
        #pragma unroll
        for (int ky = 0; ky < 3; ++ky) {
            const float* r0 = &xpad[ci][y0 + ky][x0];
            const float* r1 = &xpad[ci][y1 + ky][x1];
            float a00 = r0[0], a01 = r0[1], a02 = r0[2];
            float a10 = r1[0], a11 = r1[1], a12 = r1[2];
            const float* wb = cw + ci * 9 + ky * 3;   // + o*54; uniform -> s_load
            #pragma unroll
            for (int o = 0; o < 15; ++o) {
                const float* wp = wb + o * 54;
                float w0 = wp[0], w1v = wp[1], w2v = wp[2];
                acc[0][o] = fmaf(a00, w0, fmaf(a01, w1v, fmaf(a02, w2v, acc[0][o])));
                acc[1][o] = fmaf(a10, w0, fmaf(a11, w1v, fmaf(a12, w2v, acc[1][o])));
            }
        }
    }
    if (!has1) {
        #pragma unroll
        for (int o = 0; o < 15; ++o) acc[1][o] = 0.0f;  // no contribution to dots
    }

    // block-wide reduce + broadcast
    auto reduce_bcast = [&](float s) -> float {
        #pragma unroll
        for (int m = 32; m; m >>= 1) s += __shfl_xor(s, m, 64);
        __syncthreads();                       // protect red[] from previous reads
        if ((tid & 63) == 0) red[tid >> 6] = s;
        __syncthreads();
        return red[0] + red[1] + red[2] + red[3];
    };

    // modified Gram-Schmidt on 5 vectors; vector d = channels 3d..3d+2 over 400 pixels
    #define DOTL(i, j)                                                              \
        (acc[0][3 * (i)] * acc[0][3 * (j)] + acc[0][3 * (i) + 1] * acc[0][3 * (j) + 1] + \
         acc[0][3 * (i) + 2] * acc[0][3 * (j) + 2] + acc[1][3 * (i)] * acc[1][3 * (j)] + \
         acc[1][3 * (i) + 1] * acc[1][3 * (j) + 1] + acc[1][3 * (i) + 2] * acc[1][3 * (j) + 2])
    #define DOT(i, j) reduce_bcast(DOTL(i, j))
    #define AXPY(i, j)                                                      \
        {                                                                   \
            _Pragma("unroll") for (int cc = 0; cc < 3; ++cc) {              \
                acc[0][3 * (i) + cc] = fmaf(-c, acc[0][3 * (j) + cc], acc[0][3 * (i) + cc]); \
                acc[1][3 * (i) + cc] = fmaf(-c, acc[1][3 * (j) + cc], acc[1][3 * (i) + cc]); \
            }                                                               \
        }

    float c;
    const float inv0 = 1.0f / DOT(0, 0);
    c = DOT(1, 0) * inv0; AXPY(1, 0);
    const float inv1 = 1.0f / DOT(1, 1);
    c = DOT(2, 0) * inv0; AXPY(2, 0);
    c = DOT(2, 1) * inv1; AXPY(2, 1);
    const float inv2 = 1.0f / DOT(2, 2);
    c = DOT(3, 0) * inv0; AXPY(3, 0);
    c = DOT(3, 1) * inv1; AXPY(3, 1);
    c = DOT(3, 2) * inv2; AXPY(3, 2);
    const float inv3 = 1.0f / DOT(3, 3);
    c = DOT(4, 0) * inv0; AXPY(4, 0);
    c = DOT(4, 1) * inv1; AXPY(4, 1);
    c = DOT(4, 2) * inv2; AXPY(4, 2);
    c = DOT(4, 3) * inv3; AXPY(4, 3);

    // write out: out[b, d, cc, y, x] with o = 3d+cc -> flat b*6000 + o*400 + p
    const size_t obase = (size_t)b * 6000;
    #pragma unroll
    for (int o = 0; o < 15; ++o) {
        out[obase + o * 400 + tid] = acc[0][o];
        if (has1) out[obase + o * 400 + tid + 256] = acc[1][o];
    }
    #undef DOTL
    #undef DOT
    #undef AXPY
}

extern "C" void kernel_launch(void* const* d_in, const int* in_sizes, int n_in,
                              void* d_out, int out_size, void* d_ws, size_t ws_size,
                              hipStream_t stream) {
    const float* x_restored  = (const float*)d_in[0];
    const float* x_distorted = (const float*)d_in[1];
    const float* w1          = (const float*)d_in[2];
    const float* w2          = (const float*)d_in[3];
    const float* b2          = (const float*)d_in[4];
    const float* conv_w      = (const float*)d_in[5];
    const float* conv_b      = (const float*)d_in[6];
    float* out = (float*)d_out;

    float* h  = (float*)d_ws;            // 8192*128 f32 = 4 MB
    float* xd = h + (size_t)NB * 128;    // 8192*1200 f32 = 39.3 MB

    mlp1_kernel<<<(NB * 128) / 256, 256, 0, stream>>>(x_distorted, w1, h);
    mlp2_kernel<<<NB / 32, 256, 0, stream>>>(h, w2, b2, xd);
    conv_gs_kernel<<<NB, 256, 0, stream>>>(xd, x_restored, conv_w, conv_b, out);
}

// Round 2
// 183.609 us; speedup vs baseline: 2.0836x; 2.0836x over previous
//
#include <hip/hip_runtime.h>

// x_restored: (8192, 3, 20, 20) f32
// x_distorted: (8192, 5) f32
// w1: (128, 5), w2: (1200, 128), b2: (1200,)
// conv_w: (15, 6, 3, 3), conv_b: (15,)
// out: (8192, 5, 3, 20, 20) f32

#define NB 8192

typedef __attribute__((ext_vector_type(8))) short short8;
typedef __attribute__((ext_vector_type(4))) float floatx4;

__device__ inline unsigned short f2bf(float f) {
    unsigned int u = __float_as_uint(f);
    unsigned int r = (u + 0x7FFFu + ((u >> 16) & 1u)) >> 16;
    return (unsigned short)r;
}

// ---------------- Kernel A: h = relu(x_distorted @ w1.T) -> bf16, (B,128) ----------------
__global__ __launch_bounds__(256) void mlp1_kernel(const float* __restrict__ xdist,
                                                   const float* __restrict__ w1,
                                                   unsigned short* __restrict__ hb) {
    int gid = blockIdx.x * 256 + threadIdx.x;
    int b = gid >> 7, j = gid & 127;
    const float* xr = xdist + b * 5;
    const float* wr = w1 + j * 5;
    float s = xr[0] * wr[0];
    s = fmaf(xr[1], wr[1], s);
    s = fmaf(xr[2], wr[2], s);
    s = fmaf(xr[3], wr[3], s);
    s = fmaf(xr[4], wr[4], s);
    hb[gid] = f2bf(fmaxf(s, 0.0f));
}

// ---------------- cast w2 -> bf16 ----------------
__global__ __launch_bounds__(256) void castw2_kernel(const float* __restrict__ w2,
                                                     unsigned short* __restrict__ w2b) {
    int i = blockIdx.x * 256 + threadIdx.x;   // 1200*128 = 153600 exactly
    w2b[i] = f2bf(w2[i]);
}

// ---------------- Kernel B: xd = h @ w2.T + b2 via bf16 MFMA ----------------
// wave-tile 64(M) x 48(N), K=128 in 4 steps of 16x16x32. N = 25*48 = 1200 exact.
// Fragments loaded directly from global (L2-resident), no LDS, no barriers.
__global__ __launch_bounds__(256) void mlp2_mfma(const unsigned short* __restrict__ hb,
                                                 const unsigned short* __restrict__ w2b,
                                                 const float* __restrict__ b2,
                                                 float* __restrict__ xd) {
    const int tid = threadIdx.x;
    const int lane = tid & 63, wv = tid >> 6;
    const int tile = blockIdx.x * 4 + wv;          // 0..3199
    const int mt = tile / 25, nt = tile - mt * 25; // 128 m-tiles x 25 n-tiles
    const int rsel = lane & 15, kg = lane >> 4;    // fragment row/col select, k-group

    short8 a[4][4], bfr[3][4];
    #pragma unroll
    for (int mi = 0; mi < 4; ++mi) {
        const unsigned short* ap = hb + (size_t)(mt * 64 + mi * 16 + rsel) * 128 + kg * 8;
        #pragma unroll
        for (int ks = 0; ks < 4; ++ks) a[mi][ks] = *(const short8*)(ap + ks * 32);
    }
    #pragma unroll
    for (int ni = 0; ni < 3; ++ni) {
        const unsigned short* bp = w2b + (size_t)(nt * 48 + ni * 16 + rsel) * 128 + kg * 8;
        #pragma unroll
        for (int ks = 0; ks < 4; ++ks) bfr[ni][ks] = *(const short8*)(bp + ks * 32);
    }
    floatx4 acc[4][3];
    #pragma unroll
    for (int mi = 0; mi < 4; ++mi)
        #pragma unroll
        for (int ni = 0; ni < 3; ++ni)
            acc[mi][ni] = (floatx4){0.f, 0.f, 0.f, 0.f};

    #pragma unroll
    for (int ks = 0; ks < 4; ++ks)
        #pragma unroll
        for (int mi = 0; mi < 4; ++mi)
            #pragma unroll
            for (int ni = 0; ni < 3; ++ni)
                acc[mi][ni] = __builtin_amdgcn_mfma_f32_16x16x32_bf16(
                    a[mi][ks], bfr[ni][ks], acc[mi][ni], 0, 0, 0);

    // C/D layout: col = lane&15 (n), row = (lane>>4)*4 + reg (m)
    #pragma unroll
    for (int ni = 0; ni < 3; ++ni) {
        float bias = b2[nt * 48 + ni * 16 + rsel];
        #pragma unroll
        for (int mi = 0; mi < 4; ++mi) {
            #pragma unroll
            for (int r = 0; r < 4; ++r) {
                int m = mt * 64 + mi * 16 + kg * 4 + r;
                xd[(size_t)m * 1200 + nt * 48 + ni * 16 + rsel] = acc[mi][ni][r] + bias;
            }
        }
    }
}

// ---------------- Kernel C: conv(6->15, 3x3 SAME) + Gram-Schmidt, ONE WAVE per sample ----
// 64 threads. Lane owns positions p = tid + 64*s, s=0..5, plus slot 6 = 384+(tid&15)
// (valid only for tid<16; computed by all lanes, zeroed after). GS reductions are pure
// intra-wave shfl butterflies -- no barriers, no LDS round trips.
__global__ __launch_bounds__(64) void conv_gs_kernel(const float* __restrict__ xd,
                                                     const float* __restrict__ xres,
                                                     const float* __restrict__ cw,
                                                     const float* __restrict__ cb,
                                                     float* __restrict__ out) {
    const int b = blockIdx.x;
    const int tid = threadIdx.x;  // 0..63
    __shared__ __align__(16) float xpad[6 * 22 * 22];  // 2904 floats, zero-padded

    // zero whole buffer (726 float4)
    float4* xf4 = (float4*)xpad;
    #pragma unroll
    for (int i = 0; i < 12; ++i) {
        int idx = tid + i * 64;
        if (idx < 726) xf4[idx] = make_float4(0.f, 0.f, 0.f, 0.f);
    }
    __syncthreads();

    // interior fill: 600 float4 (channels 0-2 = xd, 3-5 = xres); 20 % 4 == 0 so no row straddle
    const float* src0 = xd + (size_t)b * 1200;
    const float* src1 = xres + (size_t)b * 1200;
    #pragma unroll
    for (int i = 0; i < 10; ++i) {
        int j = tid + i * 64;
        if (j < 600) {
            float4 v = (j < 300) ? ((const float4*)src0)[j] : ((const float4*)src1)[j - 300];
            int c = j / 100, rr = (j % 100) * 4, y = rr / 20, x = rr % 20;
            float* dst = xpad + c * 484 + (y + 1) * 22 + (x + 1);
            dst[0] = v.x; dst[1] = v.y; dst[2] = v.z; dst[3] = v.w;
        }
    }
    __syncthreads();

    // conv: acc[slot][out_channel], bias init
    float acc[7][15];
    #pragma unroll
    for (int o = 0; o < 15; ++o) {
        float bo = cb[o];
        #pragma unroll
        for (int s = 0; s < 7; ++s) acc[s][o] = bo;
    }
    int base[7];
    #pragma unroll
    for (int s = 0; s < 7; ++s) {
        int p = (s < 6) ? (tid + 64 * s) : (384 + (tid & 15));
        int y = p / 20, x = p % 20;
        base[s] = y * 22 + x;  // window top-left in padded plane
    }

    #pragma unroll
    for (int ci = 0; ci < 6; ++ci) {
        #pragma unroll
        for (int ky = 0; ky < 3; ++ky) {
            float win[7][3];
            #pragma unroll
            for (int s = 0; s < 7; ++s) {
                const float* rp = xpad + ci * 484 + ky * 22 + base[s];
                win[s][0] = rp[0]; win[s][1] = rp[1]; win[s][2] = rp[2];
            }
            const float* wb = cw + ci * 9 + ky * 3;  // + o*54, uniform -> s_load
            #pragma unroll
            for (int o = 0; o < 15; ++o) {
                float w0 = wb[o * 54 + 0], w1v = wb[o * 54 + 1], w2v = wb[o * 54 + 2];
                #pragma unroll
                for (int s = 0; s < 7; ++s)
                    acc[s][o] = fmaf(win[s][0], w0,
                                fmaf(win[s][1], w1v,
                                fmaf(win[s][2], w2v, acc[s][o])));
            }
        }
    }
    // invalidate slot 6 for lanes >= 16 (branchless)
    float m6 = (tid < 16) ? 1.f : 0.f;
    #pragma unroll
    for (int o = 0; o < 15; ++o) acc[6][o] *= m6;

    // wave-wide butterfly sum: result in every lane, no barriers
    auto rsum = [](float v) {
        #pragma unroll
        for (int m = 32; m; m >>= 1) v += __shfl_xor(v, m, 64);
        return v;
    };

    float c;
    #define D3(s, i, j) (acc[s][3*(i)] * acc[s][3*(j)] + \
                         acc[s][3*(i)+1] * acc[s][3*(j)+1] + \
                         acc[s][3*(i)+2] * acc[s][3*(j)+2])
    #define DOTL(i, j) (D3(0,i,j) + D3(1,i,j) + D3(2,i,j) + D3(3,i,j) + \
                        D3(4,i,j) + D3(5,i,j) + D3(6,i,j))
    #define DOT(i, j) rsum(DOTL(i, j))
    #define AXPY(i, j) { _Pragma("unroll") for (int s = 0; s < 7; ++s) { \
        acc[s][3*(i)]   = fmaf(-c, acc[s][3*(j)],   acc[s][3*(i)]);   \
        acc[s][3*(i)+1] = fmaf(-c, acc[s][3*(j)+1], acc[s][3*(i)+1]); \
        acc[s][3*(i)+2] = fmaf(-c, acc[s][3*(j)+2], acc[s][3*(i)+2]); } }

    const float inv0 = 1.0f / DOT(0, 0);
    c = DOT(1, 0) * inv0; AXPY(1, 0);
    const float inv1 = 1.0f / DOT(1, 1);
    c = DOT(2, 0) * inv0; AXPY(2, 0);
    c = DOT(2, 1) * inv1; AXPY(2, 1);
    const float inv2 = 1.0f / DOT(2, 2);
    c = DOT(3, 0) * inv0; AXPY(3, 0);
    c = DOT(3, 1) * inv1; AXPY(3, 1);
    c = DOT(3, 2) * inv2; AXPY(3, 2);
    const float inv3 = 1.0f / DOT(3, 3);
    c = DOT(4, 0) * inv0; AXPY(4, 0);
    c = DOT(4, 1) * inv1; AXPY(4, 1);
    c = DOT(4, 2) * inv2; AXPY(4, 2);
    c = DOT(4, 3) * inv3; AXPY(4, 3);
    #undef D3
    #undef DOTL
    #undef DOT
    #undef AXPY

    // write out: flat b*6000 + o*400 + p, coalesced 256B per (o,s)
    const size_t obase = (size_t)b * 6000;
    #pragma unroll
    for (int o = 0; o < 15; ++o) {
        #pragma unroll
        for (int s = 0; s < 6; ++s)
            out[obase + o * 400 + tid + 64 * s] = acc[s][o];
    }
    if (tid < 16) {
        #pragma unroll
        for (int o = 0; o < 15; ++o)
            out[obase + o * 400 + 384 + tid] = acc[6][o];
    }
}

extern "C" void kernel_launch(void* const* d_in, const int* in_sizes, int n_in,
                              void* d_out, int out_size, void* d_ws, size_t ws_size,
                              hipStream_t stream) {
    const float* x_restored  = (const float*)d_in[0];
    const float* x_distorted = (const float*)d_in[1];
    const float* w1          = (const float*)d_in[2];
    const float* w2          = (const float*)d_in[3];
    const float* b2          = (const float*)d_in[4];
    const float* conv_w      = (const float*)d_in[5];
    const float* conv_b      = (const float*)d_in[6];
    float* out = (float*)d_out;

    float* xd = (float*)d_ws;                                  // 8192*1200 f32 = 39.3 MB
    unsigned short* hb  = (unsigned short*)(xd + (size_t)NB * 1200);  // 8192*128 bf16 = 2 MB
    unsigned short* w2b = hb + (size_t)NB * 128;               // 1200*128 bf16 = 0.3 MB

    mlp1_kernel<<<(NB * 128) / 256, 256, 0, stream>>>(x_distorted, w1, hb);
    castw2_kernel<<<(1200 * 128) / 256, 256, 0, stream>>>(w2, w2b);
    mlp2_mfma<<<(128 * 25) / 4, 256, 0, stream>>>(hb, w2b, b2, xd);
    conv_gs_kernel<<<NB, 64, 0, stream>>>(xd, x_restored, conv_w, conv_b, out);
}

// Round 3
// 174.529 us; speedup vs baseline: 2.1920x; 1.0520x over previous
//
#include <hip/hip_runtime.h>

// x_restored: (8192, 3, 20, 20) f32
// x_distorted: (8192, 5) f32
// w1: (128, 5), w2: (1200, 128), b2: (1200,)
// conv_w: (15, 6, 3, 3), conv_b: (15,)
// out: (8192, 5, 3, 20, 20) f32

#define NB 8192

typedef __attribute__((ext_vector_type(8))) short short8;
typedef __attribute__((ext_vector_type(4))) float floatx4;

__device__ inline unsigned short f2bf(float f) {
    unsigned int u = __float_as_uint(f);
    unsigned int r = (u + 0x7FFFu + ((u >> 16) & 1u)) >> 16;
    return (unsigned short)r;
}

// ---------------- Kernel A: h = relu(x_distorted @ w1.T) -> bf16, (B,128) ----------------
__global__ __launch_bounds__(256) void mlp1_kernel(const float* __restrict__ xdist,
                                                   const float* __restrict__ w1,
                                                   unsigned short* __restrict__ hb) {
    int gid = blockIdx.x * 256 + threadIdx.x;
    int b = gid >> 7, j = gid & 127;
    const float* xr = xdist + b * 5;
    const float* wr = w1 + j * 5;
    float s = xr[0] * wr[0];
    s = fmaf(xr[1], wr[1], s);
    s = fmaf(xr[2], wr[2], s);
    s = fmaf(xr[3], wr[3], s);
    s = fmaf(xr[4], wr[4], s);
    hb[gid] = f2bf(fmaxf(s, 0.0f));
}

// ---------------- cast w2 -> bf16 ----------------
__global__ __launch_bounds__(256) void castw2_kernel(const float* __restrict__ w2,
                                                     unsigned short* __restrict__ w2b) {
    int i = blockIdx.x * 256 + threadIdx.x;   // 1200*128 = 153600 exactly
    w2b[i] = f2bf(w2[i]);
}

// ---------------- Kernel B: xd = h @ w2.T + b2 via bf16 MFMA ----------------
// wave-tile 64(M) x 48(N), K=128 in 4 steps of 16x16x32. N = 25*48 = 1200 exact.
__global__ __launch_bounds__(256) void mlp2_mfma(const unsigned short* __restrict__ hb,
                                                 const unsigned short* __restrict__ w2b,
                                                 const float* __restrict__ b2,
                                                 float* __restrict__ xd) {
    const int tid = threadIdx.x;
    const int lane = tid & 63, wv = tid >> 6;
    const int tile = blockIdx.x * 4 + wv;          // 0..3199
    const int mt = tile / 25, nt = tile - mt * 25; // 128 m-tiles x 25 n-tiles
    const int rsel = lane & 15, kg = lane >> 4;

    short8 a[4][4], bfr[3][4];
    #pragma unroll
    for (int mi = 0; mi < 4; ++mi) {
        const unsigned short* ap = hb + (size_t)(mt * 64 + mi * 16 + rsel) * 128 + kg * 8;
        #pragma unroll
        for (int ks = 0; ks < 4; ++ks) a[mi][ks] = *(const short8*)(ap + ks * 32);
    }
    #pragma unroll
    for (int ni = 0; ni < 3; ++ni) {
        const unsigned short* bp = w2b + (size_t)(nt * 48 + ni * 16 + rsel) * 128 + kg * 8;
        #pragma unroll
        for (int ks = 0; ks < 4; ++ks) bfr[ni][ks] = *(const short8*)(bp + ks * 32);
    }
    floatx4 acc[4][3];
    #pragma unroll
    for (int mi = 0; mi < 4; ++mi)
        #pragma unroll
        for (int ni = 0; ni < 3; ++ni)
            acc[mi][ni] = (floatx4){0.f, 0.f, 0.f, 0.f};

    #pragma unroll
    for (int ks = 0; ks < 4; ++ks)
        #pragma unroll
        for (int mi = 0; mi < 4; ++mi)
            #pragma unroll
            for (int ni = 0; ni < 3; ++ni)
                acc[mi][ni] = __builtin_amdgcn_mfma_f32_16x16x32_bf16(
                    a[mi][ks], bfr[ni][ks], acc[mi][ni], 0, 0, 0);

    #pragma unroll
    for (int ni = 0; ni < 3; ++ni) {
        float bias = b2[nt * 48 + ni * 16 + rsel];
        #pragma unroll
        for (int mi = 0; mi < 4; ++mi) {
            #pragma unroll
            for (int r = 0; r < 4; ++r) {
                int m = mt * 64 + mi * 16 + kg * 4 + r;
                xd[(size_t)m * 1200 + nt * 48 + ni * 16 + rsel] = acc[mi][ni][r] + bias;
            }
        }
    }
}

// ---------------- Kernel C: conv(6->15, 3x3 SAME) + Gram-Schmidt, ONE WAVE per sample ----
// Strip layout: lane l (<60) owns row r = l/3, x-range [x0, x0+6], x0 = (l%3)*7
// (strip widths 7/7/6; slot 6 of j==2 strips and lanes >= 60 are masked to zero).
// Window loads: 9 shared f32 per (ci,ky) instead of 21. launch_bounds(64,2) ->
// up to 256 VGPRs so acc[7][15] lives in registers through GS.
__global__ __launch_bounds__(64, 2) void conv_gs_kernel(const float* __restrict__ xd,
                                                        const float* __restrict__ xres,
                                                        const float* __restrict__ cw,
                                                        const float* __restrict__ cb,
                                                        float* __restrict__ out) {
    const int b = blockIdx.x;
    const int tid = threadIdx.x;  // 0..63
    __shared__ __align__(16) float xpad[2908];  // 6*22*22 zero-padded planes + 4 pad

    // zero whole buffer (727 float4 = 2908 floats)
    float4* xf4 = (float4*)xpad;
    #pragma unroll
    for (int i = 0; i < 12; ++i) {
        int idx = tid + i * 64;
        if (idx < 727) xf4[idx] = make_float4(0.f, 0.f, 0.f, 0.f);
    }
    __syncthreads();

    // interior fill: 600 float4 (channels 0-2 = xd, 3-5 = xres); rows of 20 are float4-clean
    const float* src0 = xd + (size_t)b * 1200;
    const float* src1 = xres + (size_t)b * 1200;
    #pragma unroll
    for (int i = 0; i < 10; ++i) {
        int j = tid + i * 64;
        if (j < 600) {
            float4 v = (j < 300) ? ((const float4*)src0)[j] : ((const float4*)src1)[j - 300];
            int c = j / 100, rr = (j % 100) * 4, y = rr / 20, x = rr % 20;
            float* dst = xpad + c * 484 + (y + 1) * 22 + (x + 1);
            dst[0] = v.x; dst[1] = v.y; dst[2] = v.z; dst[3] = v.w;
        }
    }
    __syncthreads();

    // strip assignment
    const int ll = (tid < 60) ? tid : 59;
    const int r  = ll / 3;
    const int j3 = ll - r * 3;
    const int x0 = j3 * 7;
    const int wbase = r * 22 + x0;   // padded-plane offset of window col 0 at ky row 0

    // conv accumulators
    float acc[7][15];
    #pragma unroll
    for (int o = 0; o < 15; ++o) {
        float bo = cb[o];
        #pragma unroll
        for (int s = 0; s < 7; ++s) acc[s][o] = bo;
    }

    #pragma unroll
    for (int ci = 0; ci < 6; ++ci) {
        #pragma unroll
        for (int ky = 0; ky < 3; ++ky) {
            const float* rp = xpad + ci * 484 + ky * 22 + wbase;
            float win[9];
            #pragma unroll
            for (int t = 0; t < 9; ++t) win[t] = rp[t];
            const float* wb = cw + ci * 9 + ky * 3;  // + o*54, uniform -> s_load
            #pragma unroll
            for (int o = 0; o < 15; ++o) {
                float w0 = wb[o * 54 + 0], w1v = wb[o * 54 + 1], w2v = wb[o * 54 + 2];
                #pragma unroll
                for (int s = 0; s < 7; ++s)
                    acc[s][o] = fmaf(win[s], w0,
                                fmaf(win[s + 1], w1v,
                                fmaf(win[s + 2], w2v, acc[s][o])));
            }
        }
    }

    // mask invalid slots: lanes >= 60 entirely; slot 6 of width-6 strips (j3==2)
    const float mAll = (tid < 60) ? 1.f : 0.f;
    const float m6   = (j3 < 2) ? mAll : 0.f;
    #pragma unroll
    for (int o = 0; o < 15; ++o) {
        #pragma unroll
        for (int s = 0; s < 6; ++s) acc[s][o] *= mAll;
        acc[6][o] *= m6;
    }

    // wave-wide butterfly sum
    auto rsum = [](float v) {
        #pragma unroll
        for (int m = 32; m; m >>= 1) v += __shfl_xor(v, m, 64);
        return v;
    };

    float c;
    #define D3(s, i, j) (acc[s][3*(i)] * acc[s][3*(j)] + \
                         acc[s][3*(i)+1] * acc[s][3*(j)+1] + \
                         acc[s][3*(i)+2] * acc[s][3*(j)+2])
    #define DOTL(i, j) (D3(0,i,j) + D3(1,i,j) + D3(2,i,j) + D3(3,i,j) + \
                        D3(4,i,j) + D3(5,i,j) + D3(6,i,j))
    #define DOT(i, j) rsum(DOTL(i, j))
    #define AXPY(i, j) { _Pragma("unroll") for (int s = 0; s < 7; ++s) { \
        acc[s][3*(i)]   = fmaf(-c, acc[s][3*(j)],   acc[s][3*(i)]);   \
        acc[s][3*(i)+1] = fmaf(-c, acc[s][3*(j)+1], acc[s][3*(i)+1]); \
        acc[s][3*(i)+2] = fmaf(-c, acc[s][3*(j)+2], acc[s][3*(i)+2]); } }

    const float inv0 = 1.0f / DOT(0, 0);
    c = DOT(1, 0) * inv0; AXPY(1, 0);
    const float inv1 = 1.0f / DOT(1, 1);
    c = DOT(2, 0) * inv0; AXPY(2, 0);
    c = DOT(2, 1) * inv1; AXPY(2, 1);
    const float inv2 = 1.0f / DOT(2, 2);
    c = DOT(3, 0) * inv0; AXPY(3, 0);
    c = DOT(3, 1) * inv1; AXPY(3, 1);
    c = DOT(3, 2) * inv2; AXPY(3, 2);
    const float inv3 = 1.0f / DOT(3, 3);
    c = DOT(4, 0) * inv0; AXPY(4, 0);
    c = DOT(4, 1) * inv1; AXPY(4, 1);
    c = DOT(4, 2) * inv2; AXPY(4, 2);
    c = DOT(4, 3) * inv3; AXPY(4, 3);
    #undef D3
    #undef DOTL
    #undef DOT
    #undef AXPY

    // write out: position p = r*20 + x0 + s, flat b*6000 + o*400 + p
    const size_t obase = (size_t)b * 6000;
    if (tid < 60) {
        const int pb = r * 20 + x0;
        #pragma unroll
        for (int o = 0; o < 15; ++o) {
            #pragma unroll
            for (int s = 0; s < 6; ++s)
                out[obase + o * 400 + pb + s] = acc[s][o];
        }
        if (j3 < 2) {
            #pragma unroll
            for (int o = 0; o < 15; ++o)
                out[obase + o * 400 + pb + 6] = acc[6][o];
        }
    }
}

extern "C" void kernel_launch(void* const* d_in, const int* in_sizes, int n_in,
                              void* d_out, int out_size, void* d_ws, size_t ws_size,
                              hipStream_t stream) {
    const float* x_restored  = (const float*)d_in[0];
    const float* x_distorted = (const float*)d_in[1];
    const float* w1          = (const float*)d_in[2];
    const float* w2          = (const float*)d_in[3];
    const float* b2          = (const float*)d_in[4];
    const float* conv_w      = (const float*)d_in[5];
    const float* conv_b      = (const float*)d_in[6];
    float* out = (float*)d_out;

    float* xd = (float*)d_ws;                                         // 39.3 MB
    unsigned short* hb  = (unsigned short*)(xd + (size_t)NB * 1200);  // 2 MB
    unsigned short* w2b = hb + (size_t)NB * 128;                      // 0.3 MB

    mlp1_kernel<<<(NB * 128) / 256, 256, 0, stream>>>(x_distorted, w1, hb);
    castw2_kernel<<<(1200 * 128) / 256, 256, 0, stream>>>(w2, w2b);
    mlp2_mfma<<<(128 * 25) / 4, 256, 0, stream>>>(hb, w2b, b2, xd);
    conv_gs_kernel<<<NB, 64, 0, stream>>>(xd, x_restored, conv_w, conv_b, out);
}